// Round 7
// baseline (95.603 us; speedup 1.0000x reference)
//
#include <hip/hip_runtime.h>
#include <hip/hip_bf16.h>
#include <math.h>

#define Bn 4
#define Cn 64
#define Pn 4096   // 64*64
#define QT 64     // q-tile per block
#define PBK 128   // p-block per flash iteration
#define NITER (Pn / PBK)
#define LOG2E 1.4426950408889634f

typedef __attribute__((ext_vector_type(8))) short short8;   // 8 bf16 (MFMA K=32 A/B frag)
typedef __attribute__((ext_vector_type(4))) short short4v;  // 4 bf16 (MFMA K=16 A/B frag)
typedef __attribute__((ext_vector_type(4))) float float4v;  // MFMA C/D frag
typedef unsigned short bfu;

__device__ __forceinline__ bfu f2bf(float x) {
    unsigned u = __float_as_uint(x);
    u = (u + 0x7fffu + ((u >> 16) & 1u)) >> 16;   // RNE; inputs finite
    return (bfu)u;
}

// ---------------------------------------------------------------------------
// Prep (unchanged): 768 blocks, 16KB LDS.
//   blocks [0,512):   knorm -> bf16 Kpc [B][P][C]  and tiled Kcp2 [B][P/16][C][16p]
//   blocks [512,768): 3x3 zero-padded box-sum * log2(e) -> S [B][C][P]
// ---------------------------------------------------------------------------
__global__ __launch_bounds__(256) void prep_kernel(const float* __restrict__ fg,
                                                   bfu* __restrict__ Kpc,
                                                   bfu* __restrict__ Kcp2,
                                                   float* __restrict__ S) {
    __shared__ float shbuf[64 * 64];
    int t = threadIdx.x;
    if (blockIdx.x < 512) {
        float* tile  = shbuf;            // [64c][32p] stride 33
        float* rnorm = shbuf + 64 * 33;
        int b  = blockIdx.x >> 7;
        int p0 = (blockIdx.x & 127) << 5;
        const float* src = fg + (size_t)b * Cn * Pn + p0;
        #pragma unroll
        for (int i = 0; i < 8; ++i) {
            int idx = i * 256 + t;
            int c = idx >> 5, p = idx & 31;
            tile[c * 33 + p] = src[(size_t)c * Pn + p];
        }
        __syncthreads();
        if (t < 32) {
            float ss = 0.f;
            #pragma unroll
            for (int c = 0; c < 64; ++c) { float v = tile[c * 33 + t]; ss += v * v; }
            rnorm[t] = 1.0f / (sqrtf(ss) + 1e-8f);
        }
        __syncthreads();
        bfu* dpc = Kpc + ((size_t)b * Pn + p0) * Cn;
        #pragma unroll
        for (int i = 0; i < 8; ++i) {
            int idx = i * 256 + t;
            int p = idx >> 6, c = idx & 63;
            dpc[(size_t)p * Cn + c] = f2bf(tile[c * 33 + p] * rnorm[p]);
        }
        // tiled transpose layout: Kcp2[b][pt][c][pl], pt = p>>4, pl = p&15
        bfu* d2 = Kcp2 + ((size_t)b * 256 + (p0 >> 4)) * 1024;
        #pragma unroll
        for (int i = 0; i < 8; ++i) {
            int idx = i * 256 + t;
            int c = idx >> 5, p = idx & 31;
            d2[(size_t)(p >> 4) * 1024 + c * 16 + (p & 15)] =
                f2bf(tile[c * 33 + p] * rnorm[p]);
        }
    } else {
        float (*pl)[64] = (float(*)[64])shbuf;
        int bc = blockIdx.x - 512;
        const float* src = fg + (size_t)bc * Pn;
        float*       dst = S  + (size_t)bc * Pn;
        #pragma unroll
        for (int i = 0; i < 16; ++i) {
            int idx = i * 256 + t;
            pl[idx >> 6][idx & 63] = src[idx];
        }
        __syncthreads();
        #pragma unroll
        for (int i = 0; i < 16; ++i) {
            int idx = i * 256 + t;
            int h = idx >> 6, w = idx & 63;
            float s = 0.f;
            #pragma unroll
            for (int dh = -1; dh <= 1; ++dh) {
                int hh = h + dh;
                if (hh < 0 || hh >= 64) continue;
                #pragma unroll
                for (int dw = -1; dw <= 1; ++dw) {
                    int ww = w + dw;
                    if (ww < 0 || ww >= 64) continue;
                    s += pl[hh][ww];
                }
            }
            dst[idx] = s * LOG2E;
        }
    }
}

// ---------------------------------------------------------------------------
// Flash (R19) = R0 champion structure with the loads made REAL prefetches:
// asm volatile global_load into named double-buffered register sets (volatile
// asm pins issue at body top; cannot sink below the closing s_waitcnt), one
// s_waitcnt vmcnt(0) + sched_barrier(0) per half-body. ~600 cyc of compute
// sits between issue and wait, so L2 latency leaves the critical path.
// Wave w owns p-rows [16w,16w+16) of each 128-p block end-to-end:
//   score: A = Kpc rows (dwordx4 + offset:64), B = hoisted S frags
//   exp'd scores -> register K=16 A-frags; accum: B = Kcp2 frags (dwordx2,
//   offset:512/1024/1536). No LDS, no barriers inside the loop.
// ---------------------------------------------------------------------------
__global__ __launch_bounds__(512, 1) void flash_kernel(const bfu* __restrict__ Kpc,
                                                       const bfu* __restrict__ Kcp2,
                                                       const float* __restrict__ S,
                                                       float* __restrict__ out) {
    // Sl lives in [0,8192) bfu; epilogue Ol fp32 [4][64][66] overlays all 67.5 KB
    __shared__ __align__(16) bfu smem[33792];
    __shared__ float wredl[8][QT];
    bfu* Sl = smem;

    int i  = blockIdx.x;
    int b  = (i & 7) >> 1;                       // XCD-pair locality
    int qt = ((i >> 3) << 1) | (i & 1);
    int q0 = qt * QT;
    int t  = threadIdx.x;
    int w = t >> 6, l = t & 63, lq = l & 15, quad = l >> 4;

    const float* Sg  = S    + (size_t)b * Cn * Pn;
    const bfu*   gpc = Kpc  + (size_t)b * Pn * Cn;
    const bfu*   gt  = Kcp2 + (size_t)b * 256 * 1024;   // [pt][c][pl]

    // Sl[q][c] = bf16(Sg[c][q0+q]) (S pre-scaled by log2e), XOR-swizzled rows
    {
        int c = t >> 3, qq = (t & 7) * 8;
        const float* sp = &Sg[(size_t)c * Pn + q0 + qq];
        float4 v0 = *(const float4*)sp;
        float4 v1 = *(const float4*)(sp + 4);
        float vv[8] = {v0.x, v0.y, v0.z, v0.w, v1.x, v1.y, v1.z, v1.w};
        int ch = c >> 3, cl = c & 7;
        #pragma unroll
        for (int k = 0; k < 8; ++k) {
            int row = qq + k;
            Sl[row * 64 + ((ch ^ (row & 7)) << 3) + cl] = f2bf(vv[k]);
        }
    }
    __syncthreads();   // Sl visible

    // hoist S B-frags: B[k=c][n=q], n=lq(+16nt), k=quad*8+j (+32ks)
    short8 bs[4][2];
    #pragma unroll
    for (int nt = 0; nt < 4; ++nt)
        #pragma unroll
        for (int ks = 0; ks < 2; ++ks) {
            int row = nt * 16 + lq;
            bs[nt][ks] = *(const short8*)&Sl[row * 64 + (((ks * 4 + quad) ^ (lq & 7)) << 3)];
        }

    float4v o[4][4];   // [nt][cb]: q = 16nt+4quad+r, c = 16cb+lq (wave-private p-partial)
    #pragma unroll
    for (int nt = 0; nt < 4; ++nt)
        #pragma unroll
        for (int cb = 0; cb < 4; ++cb) o[nt][cb] = (float4v){0.f, 0.f, 0.f, 0.f};
    float lacc[4] = {0.f, 0.f, 0.f, 0.f};

    // per-wave global base addresses (advance by +8192 elements per tile)
    const bfu* ap = gpc + ((size_t)16 * w + lq) * Cn + quad * 8;           // score A rows
    const bfu* tp = gt + (size_t)w * 1024 + lq * 16 + quad * 4;            // accum B frags

    // double-buffered asm register sets (named; rule-20 static)
    float4v a0A, a1A, a0B, a1B;
    short4v k0A, k1A, k2A, k3A, k0B, k1B, k2B, k3B;

    // LOADSET: volatile asm loads — pinned at body top, one base addr per
    // operand stream, offset: immediates for the rest (<= 1536 B).
    #define LOADSET(suf, aptr, tptr)                                                        \
        asm volatile("global_load_dwordx4 %0, %1, off"             : "=v"(a0##suf) : "v"(aptr)); \
        asm volatile("global_load_dwordx4 %0, %1, off offset:64"   : "=v"(a1##suf) : "v"(aptr)); \
        asm volatile("global_load_dwordx2 %0, %1, off"             : "=v"(k0##suf) : "v"(tptr)); \
        asm volatile("global_load_dwordx2 %0, %1, off offset:512"  : "=v"(k1##suf) : "v"(tptr)); \
        asm volatile("global_load_dwordx2 %0, %1, off offset:1024" : "=v"(k2##suf) : "v"(tptr)); \
        asm volatile("global_load_dwordx2 %0, %1, off offset:1536" : "=v"(k3##suf) : "v"(tptr));

    #define WAITLOADS()                                        \
        asm volatile("s_waitcnt vmcnt(0)" ::: "memory");       \
        __builtin_amdgcn_sched_barrier(0);

    // COMPUTE: identical math to R0 (score K=32 MFMA x8, exp2+pack, accum K=16 x16)
    #define COMPUTE(suf)                                                                     \
    {                                                                                        \
        short8 af0 = *(short8*)&a0##suf, af1 = *(short8*)&a1##suf;                           \
        float4v sc[4];                                                                       \
        _Pragma("unroll")                                                                    \
        for (int nt = 0; nt < 4; ++nt) {                                                     \
            float4v acc = (float4v){0.f, 0.f, 0.f, 0.f};                                     \
            acc = __builtin_amdgcn_mfma_f32_16x16x32_bf16(af0, bs[nt][0], acc, 0, 0, 0);     \
            acc = __builtin_amdgcn_mfma_f32_16x16x32_bf16(af1, bs[nt][1], acc, 0, 0, 0);     \
            sc[nt] = acc;                                                                    \
        }                                                                                    \
        short4v epk[4];                                                                      \
        _Pragma("unroll")                                                                    \
        for (int nt = 0; nt < 4; ++nt) {                                                     \
            float e0 = __builtin_amdgcn_exp2f(sc[nt][0]);                                    \
            float e1 = __builtin_amdgcn_exp2f(sc[nt][1]);                                    \
            float e2 = __builtin_amdgcn_exp2f(sc[nt][2]);                                    \
            float e3 = __builtin_amdgcn_exp2f(sc[nt][3]);                                    \
            lacc[nt] += (e0 + e1) + (e2 + e3);                                               \
            short4v ep = {(short)f2bf(e0), (short)f2bf(e1), (short)f2bf(e2), (short)f2bf(e3)}; \
            epk[nt] = ep;                                                                    \
        }                                                                                    \
        _Pragma("unroll")                                                                    \
        for (int nt = 0; nt < 4; ++nt) {                                                     \
            o[nt][0] = __builtin_amdgcn_mfma_f32_16x16x16bf16_1k(epk[nt], k0##suf, o[nt][0], 0, 0, 0); \
            o[nt][1] = __builtin_amdgcn_mfma_f32_16x16x16bf16_1k(epk[nt], k1##suf, o[nt][1], 0, 0, 0); \
            o[nt][2] = __builtin_amdgcn_mfma_f32_16x16x16bf16_1k(epk[nt], k2##suf, o[nt][2], 0, 0, 0); \
            o[nt][3] = __builtin_amdgcn_mfma_f32_16x16x16bf16_1k(epk[nt], k3##suf, o[nt][3], 0, 0, 0); \
        }                                                                                    \
    }

    // prologue: load tile 0 into set A
    LOADSET(A, ap, tp);
    WAITLOADS();

    for (int pbb = 0; pbb < NITER / 2; ++pbb) {
        // even half: load tile 2pbb+1 into B, compute tile 2pbb from A
        LOADSET(B, ap + 8192, tp + 8192);
        COMPUTE(A);
        WAITLOADS();
        // odd half: load tile 2pbb+2 into A, compute tile 2pbb+1 from B
        ap += 16384; tp += 16384;
        // (final iteration loads one tile past the end: lands in the next
        //  workspace buffer -- allocated memory, values never consumed)
        LOADSET(A, ap, tp);
        COMPUTE(B);
        WAITLOADS();
    }
    #undef LOADSET
    #undef WAITLOADS
    #undef COMPUTE

    // ---- denominator: quad-reduce then stash per wave ----
    #pragma unroll
    for (int nt = 0; nt < 4; ++nt) {
        lacc[nt] += __shfl_xor(lacc[nt], 16);
        lacc[nt] += __shfl_xor(lacc[nt], 32);
    }
    if (quad == 0)
        #pragma unroll
        for (int nt = 0; nt < 4; ++nt) wredl[w][nt * 16 + lq] = lacc[nt];

    // ---- cross-wave combine via LDS overlay (2 rounds) ----
    float* Ol = (float*)smem;   // [4][64 c][66] fp32 = 67584 B
    __syncthreads();            // Sl reads done; wredl visible
    if (w < 4) {
        #pragma unroll
        for (int nt = 0; nt < 4; ++nt)
            #pragma unroll
            for (int cb = 0; cb < 4; ++cb)
                #pragma unroll
                for (int r = 0; r < 4; ++r)
                    Ol[(w * 64 + 16 * cb + lq) * 66 + nt * 16 + quad * 4 + r] = o[nt][cb][r];
    }
    __syncthreads();
    if (w >= 4) {
        #pragma unroll
        for (int nt = 0; nt < 4; ++nt)
            #pragma unroll
            for (int cb = 0; cb < 4; ++cb)
                #pragma unroll
                for (int r = 0; r < 4; ++r)
                    Ol[((w - 4) * 64 + 16 * cb + lq) * 66 + nt * 16 + quad * 4 + r] += o[nt][cb][r];
    }
    __syncthreads();

    // ---- final: out[c][q0+q] = sum of 4 buffers / l_q ----
    float* og = out + (size_t)b * Cn * Pn;
    #pragma unroll
    for (int k = 0; k < 8; ++k) {
        int idx = k * 512 + t;
        int c = idx >> 6, q = idx & 63;
        float lsum = ((wredl[0][q] + wredl[1][q]) + (wredl[2][q] + wredl[3][q])) +
                     ((wredl[4][q] + wredl[5][q]) + (wredl[6][q] + wredl[7][q]));
        float v = ((Ol[c * 66 + q] + Ol[(64 + c) * 66 + q]) +
                   (Ol[(128 + c) * 66 + q] + Ol[(192 + c) * 66 + q])) / lsum;
        og[(size_t)c * Pn + q0 + q] = v;
    }
}

// ---------------------------------------------------------------------------
extern "C" void kernel_launch(void* const* d_in, const int* in_sizes, int n_in,
                              void* d_out, int out_size, void* d_ws, size_t ws_size,
                              hipStream_t stream) {
    const float* fg = (const float*)d_in[0];
    float* out = (float*)d_out;
    bfu*   Kpc  = (bfu*)d_ws;                              // 2 MB  bf16 [B][P][C]
    bfu*   Kcp2 = Kpc + (size_t)Bn * Pn * Cn;              // 2 MB  bf16 [B][P/16][C][16]
    float* S    = (float*)(Kcp2 + (size_t)Bn * Pn * Cn);   // 4 MB  fp32 [B][C][P] (pre-scaled by log2e)

    prep_kernel <<<768, 256, 0, stream>>>(fg, Kpc, Kcp2, S);
    flash_kernel<<<Bn * 64, 512, 0, stream>>>(Kpc, Kcp2, S, out);
}